// Round 4
// baseline (636.249 us; speedup 1.0000x reference)
//
#include <hip/hip_runtime.h>
#include <hip/hip_bf16.h>

typedef __attribute__((ext_vector_type(8))) short short8;
typedef __attribute__((ext_vector_type(4))) float float4v;

#define BM 128
#define BK 32
#define LDSK 40   // old fallback path

struct alignas(8) BF4 { unsigned short x, y, z, w; };
struct alignas(16) BF8 { unsigned short s[8]; };
struct alignas(16) I4 { int x, y, z, w; };

__device__ __forceinline__ unsigned short f2bf(float f) {
    union { float f; unsigned u; } v; v.f = f;
    unsigned u = v.u + (0x7FFFu + ((v.u >> 16) & 1u));   // RNE
    return (unsigned short)(u >> 16);
}

__device__ __forceinline__ int find_expert(const int* __restrict__ bspe, int row0) {
    int e = 0, off = 0;
    #pragma unroll
    for (int i = 0; i < 8; ++i) {
        int s = bspe[i];
        if (row0 < off + s) { e = i; break; }
        off += s;
    }
    return e;
}

__device__ __forceinline__ void gload_lds16(const unsigned short* g, unsigned short* l) {
    __builtin_amdgcn_global_load_lds(
        (const __attribute__((address_space(1))) void*)g,
        (__attribute__((address_space(3))) void*)l, 16, 0, 0);
}

// ---------------------------------------------------------------------------
// fp32 -> bf16 conversion bodies
// ---------------------------------------------------------------------------
__device__ __forceinline__ void conv_body(const float* __restrict__ src,
                                          unsigned short* __restrict__ dst,
                                          long n, int b0, int nb) {
    const long stride = (long)nb * 256 * 8;
    for (long i = ((long)b0 * 256 + threadIdx.x) * 8; i < n; i += stride) {
        const float4 v0 = *(const float4*)(src + i);
        const float4 v1 = *(const float4*)(src + i + 4);
        BF8 o;
        o.s[0] = f2bf(v0.x); o.s[1] = f2bf(v0.y); o.s[2] = f2bf(v0.z); o.s[3] = f2bf(v0.w);
        o.s[4] = f2bf(v1.x); o.s[5] = f2bf(v1.y); o.s[6] = f2bf(v1.z); o.s[7] = f2bf(v1.w);
        *(BF8*)(dst + i) = o;
    }
}

__global__ __launch_bounds__(256) void f32_to_bf16(const float* __restrict__ src,
                                                   unsigned short* __restrict__ dst,
                                                   long n) {
    conv_body(src, dst, n, blockIdx.x, gridDim.x);
}

// x + wug in one launch (grid 4096)
__global__ __launch_bounds__(256) void convert2(const float* __restrict__ x, unsigned short* __restrict__ xb,
                                                const float* __restrict__ wug, unsigned short* __restrict__ wb) {
    const int b = blockIdx.x;
    if (b < 2048) conv_body(x, xb, 16384L * 2048L, b, 2048);
    else          conv_body(wug, wb, 16384L * 2048L, b - 2048, 2048);
}

// x + wug + wd in one launch (grid 5120) -- only when wdb has its own region
__global__ __launch_bounds__(256) void convert3(const float* __restrict__ x, unsigned short* __restrict__ xb,
                                                const float* __restrict__ wug, unsigned short* __restrict__ wb,
                                                const float* __restrict__ wd, unsigned short* __restrict__ wdb) {
    const int b = blockIdx.x;
    if (b < 2048)      conv_body(x, xb, 16384L * 2048L, b, 2048);
    else if (b < 4096) conv_body(wug, wb, 16384L * 2048L, b - 2048, 2048);
    else               conv_body(wd, wdb, 2048L * 8192L, b - 4096, 1024);
}

// ===========================================================================
// 8-wave 256x256 deep-pipelined GEMMs.  LDS per operand:
// [buf:2][ks:2][256 rows][32 cols] bf16 (16 KiB/region, 128 KiB total).
// Swizzle: 16B granule g' = g ^ ((row>>1)&3); stage = pre-swizzled global src
// with linear LDS dest; read applies the same involution.
//
// Register-pipelined 4-phase schedule (counted lgkm waits):
//   fragments for phase p are ds_read-issued in phase p-1; phase p's MMA
//   gates on lgkmcnt(N) where N = reads just issued for p+1.  LDS pipe runs
//   one phase ahead, fully under the MFMA shadow.
// Per K-tile t (buf=t&1):
//   ph0: STG_A(t+1,ks1) | BAR | rd a1<-A(ks0,mh1)[4]          | lgkm(4) MMA(a0,b0,mh0) | BAR
//   ph1: STG_B(t+1,ks1) vm(8) | BAR | rd b1<-B(ks1), a0<-A(ks1,mh0)[8] | lgkm(8) MMA(a1,b0,mh1) | BAR
//   ph2: STG_A(t+2,ks0) | BAR | rd a1<-A(ks1,mh1)[4]          | lgkm(4) MMA(a0,b1,mh0) | BAR
//   ph3: STG_B(t+2,ks0) vm(8) | BAR | rd b0,a0 <- (buf^1,ks0)[8] | lgkm(8) MMA(a1,b1,mh1) | BAR
// Hazard audit (per region): last reader drains under a counted lgkm gate
// BEFORE the barrier preceding the STG that overwrites it; every read of
// staged data sits behind a counted vmcnt whose 8-newest window excludes
// that region's staging, + barrier for cross-thread visibility.  Tails:
// ph1 t==NKT-1 -> vm(0); ph3 t==NKT-2 -> vm(4); ph3 t==NKT-1 -> lgkm(0).
// ===========================================================================
#define BAR() __builtin_amdgcn_s_barrier()
#define WAITV(n) do { asm volatile("s_waitcnt vmcnt(" #n ")" ::: "memory"); \
                      __builtin_amdgcn_sched_barrier(0); } while (0)
#define WAITLC(n) do { asm volatile("s_waitcnt lgkmcnt(" #n ")" ::: "memory"); \
                       __builtin_amdgcn_sched_barrier(0); } while (0)

#define STG_A(tt, kss) do { \
    gload_lds16(pA0 + (long)(tt) * 64 + (kss) * 32, As + ((((tt)&1)*2 + (kss))*8192) + 0*4096 + w*512); \
    gload_lds16(pA1 + (long)(tt) * 64 + (kss) * 32, As + ((((tt)&1)*2 + (kss))*8192) + 1*4096 + w*512); \
} while (0)
#define STG_B(tt, kss) do { \
    gload_lds16(pB0 + (long)(tt) * 64 + (kss) * 32, Bs + ((((tt)&1)*2 + (kss))*8192) + 0*4096 + w*512); \
    gload_lds16(pB1 + (long)(tt) * 64 + (kss) * 32, Bs + ((((tt)&1)*2 + (kss))*8192) + 1*4096 + w*512); \
} while (0)

#define RD_A4(dst, buf_, ks_, mh_) do { \
    const unsigned short* _p = As + (((buf_)*2 + (ks_))*8192) + gA + (arow + (mh_)*64)*32; \
    dst[0] = *(const short8*)(_p);        dst[1] = *(const short8*)(_p + 512); \
    dst[2] = *(const short8*)(_p + 1024); dst[3] = *(const short8*)(_p + 1536); \
} while (0)
#define RD_B4(dst, buf_, ks_) do { \
    const unsigned short* _p = Bs + (((buf_)*2 + (ks_))*8192) + gA + brow*32; \
    dst[0] = *(const short8*)(_p);        dst[1] = *(const short8*)(_p + 512); \
    dst[2] = *(const short8*)(_p + 1024); dst[3] = *(const short8*)(_p + 1536); \
} while (0)

#define MMA_AB(A_, B_, mh_) do { \
    __builtin_amdgcn_s_setprio(1); \
    _Pragma("unroll") \
    for (int _j = 0; _j < 4; ++_j) \
        _Pragma("unroll") \
        for (int _n = 0; _n < 4; ++_n) \
            acc[(mh_)*4 + _j][_n] = __builtin_amdgcn_mfma_f32_16x16x32_bf16(A_[_j], B_[_n], acc[(mh_)*4 + _j][_n], 0, 0, 0); \
    __builtin_amdgcn_s_setprio(0); \
} while (0)

#define KLOOP(NKT) \
    short8 a0[4], a1[4], b0[4], b1[4]; \
    STG_A(0, 0); STG_B(0, 0); \
    STG_A(0, 1); STG_B(0, 1); \
    STG_A(1, 0); STG_B(1, 0); \
    WAITV(8); \
    BAR(); \
    RD_B4(b0, 0, 0); RD_A4(a0, 0, 0, 0); \
    for (int t = 0; t < (NKT); ++t) { \
        const int buf = t & 1; \
        /* ph0 */ \
        if (t < (NKT) - 1) STG_A(t + 1, 1); \
        BAR(); \
        RD_A4(a1, buf, 0, 1); \
        WAITLC(4); \
        MMA_AB(a0, b0, 0); \
        BAR(); \
        /* ph1 */ \
        if (t < (NKT) - 1) { STG_B(t + 1, 1); WAITV(8); } else { WAITV(0); } \
        BAR(); \
        RD_B4(b1, buf, 1); RD_A4(a0, buf, 1, 0); \
        WAITLC(8); \
        MMA_AB(a1, b0, 1); \
        BAR(); \
        /* ph2 */ \
        if (t < (NKT) - 2) STG_A(t + 2, 0); \
        BAR(); \
        RD_A4(a1, buf, 1, 1); \
        WAITLC(4); \
        MMA_AB(a0, b1, 0); \
        BAR(); \
        /* ph3 */ \
        if (t < (NKT) - 2) { STG_B(t + 2, 0); WAITV(8); } \
        else if (t == (NKT) - 2) { WAITV(4); } \
        BAR(); \
        if (t < (NKT) - 1) { RD_B4(b0, buf ^ 1, 0); RD_A4(a0, buf ^ 1, 0, 0); WAITLC(8); } \
        else { WAITLC(0); } \
        MMA_AB(a1, b1, 1); \
        BAR(); \
    }

// Kernel 1: h = silu(x@Wu^T) * (x@Wg^T).  Block 256 rows x 128 h-cols
// (256 virtual B rows; within each wave's 64-col block, rows 0-31 = up,
// 32-63 = gate of the same 32 h-cols).  grid (8, 64), 512 threads.
__global__ __launch_bounds__(512) void moe_up_gate_p8(
    const unsigned short* __restrict__ xb, const unsigned short* __restrict__ wb,
    const int* __restrict__ bspe, unsigned short* __restrict__ hws) {
    __shared__ alignas(16) unsigned short As[32768];
    __shared__ alignas(16) unsigned short Bs[32768];

    const int t0 = threadIdx.x;
    const int lane = t0 & 63;
    const int w = t0 >> 6;                 // 0..7
    const int wr = w >> 2, wc = w & 3;
    const int row0 = blockIdx.y * 256;
    const int h0 = blockIdx.x * 128;
    const int e = find_expert(bspe, row0);

    const int srow = lane >> 2;                              // 0..15
    const int gs = ((lane & 3) ^ ((lane >> 3) & 3)) * 8;     // pre-swizzled src granule
    const unsigned short* pA0 = xb + (long)(row0 + w * 16 + srow) * 2048 + gs;
    const unsigned short* pA1 = pA0 + (long)128 * 2048;
    const unsigned short* pB0; const unsigned short* pB1;
    {
        const int r0 = w * 16 + srow;
        const int r1 = r0 + 128;
        const int in0 = r0 & 63, in1 = r1 & 63;
        const long g0 = (long)e * 2048 + (in0 < 32 ? 0 : 1024) + h0 + (r0 >> 6) * 32 + (in0 & 31);
        const long g1 = (long)e * 2048 + (in1 < 32 ? 0 : 1024) + h0 + (r1 >> 6) * 32 + (in1 & 31);
        pB0 = wb + g0 * 2048 + gs;
        pB1 = wb + g1 * 2048 + gs;
    }

    const int l15 = lane & 15;
    const int gA = ((lane >> 4) ^ ((l15 >> 1) & 3)) * 8;
    const int arow = wr * 128 + l15;
    const int brow = wc * 64 + l15;

    float4v acc[8][4];
    #pragma unroll
    for (int m = 0; m < 8; ++m)
        #pragma unroll
        for (int n = 0; n < 4; ++n)
            acc[m][n] = (float4v){0.f, 0.f, 0.f, 0.f};

    KLOOP(32)

    const int rbase = row0 + wr * 128 + (lane >> 4) * 4;
    const int cbase = h0 + wc * 32 + l15;
    #pragma unroll
    for (int m = 0; m < 8; ++m)
        #pragma unroll
        for (int n = 0; n < 2; ++n)
            #pragma unroll
            for (int q = 0; q < 4; ++q) {
                const float u = acc[m][n][q];
                const float g = acc[m][n + 2][q];
                const float s = u / (1.f + __expf(-u));
                hws[(long)(rbase + m * 16 + q) * 1024 + cbase + n * 16] = f2bf(s * g);
            }
}

// Kernel 2: out = h @ Wd_e^T.  Block 256x256.  grid (8, 64), 512 threads.
__global__ __launch_bounds__(512) void moe_down_p8(
    const unsigned short* __restrict__ hws, const unsigned short* __restrict__ wdb,
    const int* __restrict__ bspe, float* __restrict__ out) {
    __shared__ alignas(16) unsigned short As[32768];
    __shared__ alignas(16) unsigned short Bs[32768];

    const int t0 = threadIdx.x;
    const int lane = t0 & 63;
    const int w = t0 >> 6;
    const int wr = w >> 2, wc = w & 3;
    const int row0 = blockIdx.y * 256;
    const int n0 = blockIdx.x * 256;
    const int e = find_expert(bspe, row0);

    const int srow = lane >> 2;
    const int gs = ((lane & 3) ^ ((lane >> 3) & 3)) * 8;
    const unsigned short* pA0 = hws + (long)(row0 + w * 16 + srow) * 1024 + gs;
    const unsigned short* pA1 = pA0 + (long)128 * 1024;
    const unsigned short* pB0 = wdb + (long)(n0 + w * 16 + srow) * 8192 + (long)e * 1024 + gs;
    const unsigned short* pB1 = pB0 + (long)128 * 8192;

    const int l15 = lane & 15;
    const int gA = ((lane >> 4) ^ ((l15 >> 1) & 3)) * 8;
    const int arow = wr * 128 + l15;
    const int brow = wc * 64 + l15;

    float4v acc[8][4];
    #pragma unroll
    for (int m = 0; m < 8; ++m)
        #pragma unroll
        for (int n = 0; n < 4; ++n)
            acc[m][n] = (float4v){0.f, 0.f, 0.f, 0.f};

    KLOOP(16)

    const int rbase = row0 + wr * 128 + (lane >> 4) * 4;
    const int cbase = n0 + wc * 64 + l15;
    #pragma unroll
    for (int m = 0; m < 8; ++m)
        #pragma unroll
        for (int n = 0; n < 4; ++n)
            #pragma unroll
            for (int q = 0; q < 4; ++q)
                out[(long)(rbase + m * 16 + q) * 2048 + cbase + n * 16] = acc[m][n][q];
}

// ---------------------------------------------------------------------------
// OLD PATH (fallback if workspace too small) -- verbatim prior verified code.
// ---------------------------------------------------------------------------
__device__ __forceinline__ void stage_f32_tile(const float* __restrict__ src, long ld,
                                               unsigned short* lds, int t) {
    const int rr  = t >> 3;
    const int col = (t & 7) << 2;
    #pragma unroll
    for (int r = 0; r < 4; ++r) {
        const int row = rr + r * 32;
        const float4 v = *(const float4*)(src + (long)row * ld + col);
        BF4 o; o.x = f2bf(v.x); o.y = f2bf(v.y); o.z = f2bf(v.z); o.w = f2bf(v.w);
        *(BF4*)(lds + row * LDSK + col) = o;
    }
}

__global__ __launch_bounds__(256) void moe_up_gate(
    const float* __restrict__ x, const float* __restrict__ wug,
    const int* __restrict__ bspe, unsigned short* __restrict__ hws) {
    __shared__ alignas(16) unsigned short As[BM * LDSK];
    __shared__ alignas(16) unsigned short Bs[BM * LDSK];

    const int t = threadIdx.x;
    const int lane = t & 63;
    const int w = t >> 6;
    const int wr = w >> 1, wc = w & 1;
    const int bm = blockIdx.y;
    const int h0 = blockIdx.x * 64;
    const int row0 = bm * BM;

    const int e = find_expert(bspe, row0);

    const float* abase = x + (long)row0 * 2048;
    const float* bup = wug + ((long)e * 2048 + h0) * 2048;
    const float* bgt = wug + ((long)e * 2048 + 1024 + h0) * 2048;

    float4v acc[4][4];
    #pragma unroll
    for (int m = 0; m < 4; ++m)
        #pragma unroll
        for (int n = 0; n < 4; ++n)
            acc[m][n] = (float4v){0.f, 0.f, 0.f, 0.f};

    const int k8 = (lane >> 4) << 3;
    const int am = wr * 64 + (lane & 15);
    const int l15 = lane & 15;

    for (int k0 = 0; k0 < 2048; k0 += BK) {
        __syncthreads();
        stage_f32_tile(abase + k0, 2048, As, t);
        {
            const int rr  = t >> 3;
            const int col = (t & 7) << 2;
            #pragma unroll
            for (int r = 0; r < 4; ++r) {
                const int row = rr + r * 32;
                const float* p = (row < 64 ? bup + (long)row * 2048
                                           : bgt + (long)(row - 64) * 2048) + k0 + col;
                const float4 v = *(const float4*)p;
                BF4 o; o.x = f2bf(v.x); o.y = f2bf(v.y); o.z = f2bf(v.z); o.w = f2bf(v.w);
                *(BF4*)(Bs + row * LDSK + col) = o;
            }
        }
        __syncthreads();

        short8 a[4], b[4];
        #pragma unroll
        for (int m = 0; m < 4; ++m)
            a[m] = *(const short8*)(As + (am + m * 16) * LDSK + k8);
        #pragma unroll
        for (int n = 0; n < 4; ++n) {
            const int rb = (n < 2) ? (wc * 32 + n * 16) : (64 + wc * 32 + (n - 2) * 16);
            b[n] = *(const short8*)(Bs + (rb + l15) * LDSK + k8);
        }
        #pragma unroll
        for (int m = 0; m < 4; ++m)
            #pragma unroll
            for (int n = 0; n < 4; ++n)
                acc[m][n] = __builtin_amdgcn_mfma_f32_16x16x32_bf16(a[m], b[n], acc[m][n], 0, 0, 0);
    }

    const int rbase = row0 + wr * 64 + (lane >> 4) * 4;
    const int cbase = h0 + wc * 32 + l15;
    #pragma unroll
    for (int m = 0; m < 4; ++m)
        #pragma unroll
        for (int n = 0; n < 2; ++n)
            #pragma unroll
            for (int q = 0; q < 4; ++q) {
                const float u = acc[m][n][q];
                const float g = acc[m][n + 2][q];
                const float s = u / (1.f + __expf(-u));
                hws[(long)(rbase + m * 16 + q) * 1024 + cbase + n * 16] = f2bf(s * g);
            }
}

__global__ __launch_bounds__(256) void moe_down(
    const unsigned short* __restrict__ hws, const float* __restrict__ wd,
    const int* __restrict__ bspe, float* __restrict__ out) {
    __shared__ alignas(16) unsigned short As[BM * LDSK];
    __shared__ alignas(16) unsigned short Bs[BM * LDSK];

    const int t = threadIdx.x;
    const int lane = t & 63;
    const int w = t >> 6;
    const int wr = w >> 1, wc = w & 1;
    const int bm = blockIdx.y;
    const int n0 = blockIdx.x * BM;
    const int row0 = bm * BM;

    const int e = find_expert(bspe, row0);

    const unsigned short* abase = hws + (long)row0 * 1024;
    const float* bbase = wd + (long)n0 * 8192 + e * 1024;

    float4v acc[4][4];
    #pragma unroll
    for (int m = 0; m < 4; ++m)
        #pragma unroll
        for (int n = 0; n < 4; ++n)
            acc[m][n] = (float4v){0.f, 0.f, 0.f, 0.f};

    const int k8 = (lane >> 4) << 3;
    const int am = wr * 64 + (lane & 15);
    const int l15 = lane & 15;

    for (int k0 = 0; k0 < 1024; k0 += BK) {
        __syncthreads();
        {
            const int row = t >> 2;
            const int col = (t & 3) << 3;
            #pragma unroll
            for (int r = 0; r < 2; ++r) {
                const I4 v = *(const I4*)(abase + (long)(row + r * 64) * 1024 + k0 + col);
                *(I4*)(As + (row + r * 64) * LDSK + col) = v;
            }
        }
        stage_f32_tile(bbase + k0, 8192, Bs, t);
        __syncthreads();

        short8 a[4], b[4];
        #pragma unroll
        for (int m = 0; m < 4; ++m)
            a[m] = *(const short8*)(As + (am + m * 16) * LDSK + k8);
        #pragma unroll
        for (int n = 0; n < 4; ++n)
            b[n] = *(const short8*)(Bs + (wc * 64 + n * 16 + l15) * LDSK + k8);
        #pragma unroll
        for (int m = 0; m < 4; ++m)
            #pragma unroll
            for (int n = 0; n < 4; ++n)
                acc[m][n] = __builtin_amdgcn_mfma_f32_16x16x32_bf16(a[m], b[n], acc[m][n], 0, 0, 0);
    }

    const int rbase = row0 + wr * 64 + (lane >> 4) * 4;
    const int cbase = n0 + wc * 64 + l15;
    #pragma unroll
    for (int m = 0; m < 4; ++m)
        #pragma unroll
        for (int n = 0; n < 4; ++n)
            #pragma unroll
            for (int q = 0; q < 4; ++q)
                out[(long)(rbase + m * 16 + q) * 2048 + cbase + n * 16] = acc[m][n][q];
}

// ---------------------------------------------------------------------------
extern "C" void kernel_launch(void* const* d_in, const int* in_sizes, int n_in,
                              void* d_out, int out_size, void* d_ws, size_t ws_size,
                              hipStream_t stream) {
    const float* x   = (const float*)d_in[0];
    const float* wug = (const float*)d_in[1];
    const float* wd  = (const float*)d_in[2];
    const int*  bspe = (const int*)d_in[3];
    float* out = (float*)d_out;

    const size_t SZ_XB  = 16384UL * 2048UL * 2UL;   // 67.1 MB bf16 x
    const size_t SZ_WB  = 16384UL * 2048UL * 2UL;   // 67.1 MB bf16 w_up_gate
    const size_t SZ_H   = 16384UL * 1024UL * 2UL;   // 33.6 MB bf16 h
    const size_t SZ_WD  = 2048UL * 8192UL * 2UL;    // 33.6 MB bf16 w_down
    const size_t NEED   = SZ_XB + SZ_WB + SZ_H;           // overlay layout
    const size_t NEED2  = SZ_XB + SZ_WB + SZ_H + SZ_WD;   // separate wdb

    if (ws_size >= NEED2) {
        unsigned short* xb  = (unsigned short*)d_ws;
        unsigned short* wb  = (unsigned short*)((char*)d_ws + SZ_XB);
        unsigned short* hws = (unsigned short*)((char*)d_ws + SZ_XB + SZ_WB);
        unsigned short* wdb = (unsigned short*)((char*)d_ws + SZ_XB + SZ_WB + SZ_H);

        convert3<<<5120, 256, 0, stream>>>(x, xb, wug, wb, wd, wdb);
        moe_up_gate_p8<<<dim3(8, 64), dim3(512), 0, stream>>>(xb, wb, bspe, hws);
        moe_down_p8<<<dim3(8, 64), dim3(512), 0, stream>>>(hws, wdb, bspe, out);
    } else if (ws_size >= NEED) {
        unsigned short* xb  = (unsigned short*)d_ws;
        unsigned short* wb  = (unsigned short*)((char*)d_ws + SZ_XB);
        unsigned short* hws = (unsigned short*)((char*)d_ws + SZ_XB + SZ_WB);
        unsigned short* wdb = (unsigned short*)d_ws;   // overlay: xb dead after up_gate

        convert2<<<4096, 256, 0, stream>>>(x, xb, wug, wb);
        moe_up_gate_p8<<<dim3(8, 64), dim3(512), 0, stream>>>(xb, wb, bspe, hws);
        f32_to_bf16<<<1024, 256, 0, stream>>>(wd, wdb, 2048L * 8192L);
        moe_down_p8<<<dim3(8, 64), dim3(512), 0, stream>>>(hws, wdb, bspe, out);
    } else {
        unsigned short* hws = (unsigned short*)d_ws;
        moe_up_gate<<<dim3(16, 128), dim3(256), 0, stream>>>(x, wug, bspe, hws);
        moe_down  <<<dim3(16, 128), dim3(256), 0, stream>>>(hws, wd, bspe, out);
    }
}